// Round 4
// baseline (753.824 us; speedup 1.0000x reference)
//
#include <hip/hip_runtime.h>

// Problem constants: B=1024, T=200, D=128, H=128
#define T_SZ 200

typedef __attribute__((ext_vector_type(8))) short    bf16x8;
typedef __attribute__((ext_vector_type(4))) float    f32x4;
typedef __attribute__((ext_vector_type(4))) int      i32x4;
typedef __attribute__((ext_vector_type(2))) unsigned u32x2;

__device__ __forceinline__ unsigned short f2bf(float f) {
  unsigned u = __builtin_bit_cast(unsigned, f);
  u += 0x7fffu + ((u >> 16) & 1u);
  return (unsigned short)(u >> 16);
}
__device__ __forceinline__ float bf2f(unsigned us) {
  unsigned v = us << 16;
  return __builtin_bit_cast(float, v);
}
__device__ __forceinline__ float sigmoid_fast(float x) {
  float e = __builtin_amdgcn_exp2f(-1.442695041f * x);
  return __builtin_amdgcn_rcpf(1.0f + e);
}
__device__ __forceinline__ float tanh_fast(float x) {
  float e = __builtin_amdgcn_exp2f(2.885390082f * x);
  return 1.0f - 2.0f * __builtin_amdgcn_rcpf(e + 1.0f);
}
__device__ __forceinline__ f32x4 unpack_bf4(u32x2 p) {
  return (f32x4){ bf2f(p.x & 0xffffu), bf2f(p.x >> 16),
                  bf2f(p.y & 0xffffu), bf2f(p.y >> 16) };
}
__device__ __forceinline__ u32x2 pack_bf4(float a, float b, float c, float d) {
  return (u32x2){ (unsigned)f2bf(a) | ((unsigned)f2bf(b) << 16),
                  (unsigned)f2bf(c) | ((unsigned)f2bf(d) << 16) };
}
// lgkmcnt(0)-only barrier: global loads/stores (vmcnt) stay in flight.
__device__ __forceinline__ void ldsbar() {
  __asm__ __volatile__("" ::: "memory");
  __builtin_amdgcn_s_waitcnt(0xc07f);  // vmcnt(63) expcnt(7) lgkmcnt(0)
  __builtin_amdgcn_s_barrier();
  __asm__ __volatile__("" ::: "memory");
}

// ---------------------------------------------------------------------------
// Kernel 1: XGC[bt][t][row16][col384] (bf16) = (x @ Wx + bias), stored as
// S^T = W^T x^T : A = W^T (static register frags), B = x^T loaded DIRECTLY
// from global (no LDS, no barriers). C output: n(lane&15)=batch row,
// m(q*4+i)=feature col -> one 8B store of 4 consecutive cols per tile.
//   cols 0..255  : x @ W_gate[0:128,:] + b_gate
//   cols 256..383: x @ W_cand[0:128,:] + b_cand
// ---------------------------------------------------------------------------
__global__ __launch_bounds__(256, 2) void xproj_kernel(
    const float* __restrict__ X,   // [B,T,D]
    const float* __restrict__ Wg,  // [256,256]
    const float* __restrict__ bg,  // [256]
    const float* __restrict__ Wc,  // [256,128]
    const float* __restrict__ bc,  // [128]
    unsigned short* __restrict__ XGC)
{
  const int tid  = threadIdx.x;
  const int lane = tid & 63;
  const int ww   = tid >> 6;   // 0..3: wave owns col-tiles ww*96 .. ww*96+80
  const int m16  = lane & 15;  // batch row within 16-tile (N dim)
  const int q    = lane >> 4;

  // A-frags: A[m=col][k=x-dim]; lane m16 = col-in-tile, holds k = kb*32+q*8+j.
  bf16x8 wf[6][4];
  float  bias[6][4];
  #pragma unroll
  for (int nt = 0; nt < 6; ++nt) {
    int cb = ww * 96 + nt * 16;
    #pragma unroll
    for (int i = 0; i < 4; ++i)
      bias[nt][i] = (cb < 256) ? bg[cb + q * 4 + i] : bc[cb - 256 + q * 4 + i];
    #pragma unroll
    for (int kb = 0; kb < 4; ++kb) {
      bf16x8 f;
      #pragma unroll
      for (int j = 0; j < 8; ++j) {
        int k = kb * 32 + q * 8 + j;
        f[j] = (cb < 256) ? (short)f2bf(Wg[(size_t)k * 256 + cb + m16])
                          : (short)f2bf(Wc[(size_t)k * 128 + cb - 256 + m16]);
      }
      wf[nt][kb] = f;
    }
  }

  // B-frags of x^T: lane n=m16 (batch row), holds k = kb*32+q*8+j -> 
  // contiguous 32B per kb from the x row. Converted to bf16 at load.
  auto loadx = [&](int g, bf16x8* xf) {
    int bt = g / 200, t = g - bt * 200;
    const float* p = X + ((size_t)(bt * 16 + m16) * T_SZ + t) * 128 + q * 8;
    #pragma unroll
    for (int kb = 0; kb < 4; ++kb) {
      f32x4 a = *(const f32x4*)(p + kb * 32);
      f32x4 b = *(const f32x4*)(p + kb * 32 + 4);
      bf16x8 f;
      f[0]=(short)f2bf(a.x); f[1]=(short)f2bf(a.y); f[2]=(short)f2bf(a.z); f[3]=(short)f2bf(a.w);
      f[4]=(short)f2bf(b.x); f[5]=(short)f2bf(b.y); f[6]=(short)f2bf(b.z); f[7]=(short)f2bf(b.w);
      xf[kb] = f;
    }
  };

  auto dopair = [&](int g, const bf16x8* xf) {
    int bt = g / 200, t = g - bt * 200;
    unsigned short* orow = XGC + ((size_t)(bt * 200 + t) * 16 + m16) * 384 + q * 4;
    #pragma unroll
    for (int nt = 0; nt < 6; ++nt) {
      f32x4 acc = { bias[nt][0], bias[nt][1], bias[nt][2], bias[nt][3] };
      #pragma unroll
      for (int kb = 0; kb < 4; ++kb)
        acc = __builtin_amdgcn_mfma_f32_16x16x32_bf16(wf[nt][kb], xf[kb], acc, 0, 0, 0);
      *(u32x2*)(orow + ww * 96 + nt * 16) = pack_bf4(acc[0], acc[1], acc[2], acc[3]);
    }
  };

  // 12800 (bt,t) pairs, 8 per wg (1600 wgs). Depth-2 register pipeline.
  const int g0 = blockIdx.x * 8;
  bf16x8 xf0[4], xf1[4];
  loadx(g0, xf0);
  loadx(g0 + 1, xf1);
  #pragma unroll 1
  for (int p = 0; p < 8; p += 2) {
    dopair(g0 + p, xf0);
    if (p + 2 < 8) loadx(g0 + p + 2, xf0);
    dopair(g0 + p + 1, xf1);
    if (p + 3 < 8) loadx(g0 + p + 3, xf1);
  }
}

// ---------------------------------------------------------------------------
// Kernel 2: GRU recurrence, transposed: batch = N dim. 64 wgs x 512 threads.
// Wave w owns feature cols [16w,16w+16) of r, u, cand, h. Thread (m16,q)
// owns batch row m16, cols 16w+q*4..+4 -> h-state in 4 registers, r*h needs
// no LDS read, state writeback = 1 ds_write_b64, Y = 1 global_store_dwordx4.
// No scalar LDS ops anywhere; all 8 waves identical work; 2 barriers/step.
// ---------------------------------------------------------------------------
__global__ __launch_bounds__(512, 1) void gru_kernel(
    const unsigned short* __restrict__ XGC,  // [bt][t][row16][col384]
    const int*   __restrict__ seq_len,
    const float* __restrict__ Wg,   // [256,256] rows 128.. = h-part
    const float* __restrict__ Wc,   // [256,128] rows 128.. = h-part
    float* __restrict__ Y)          // [B,T,H]
{
  __shared__ unsigned short h16[16 * 136];   // h bf16, [batch row][col] pad->136
  __shared__ unsigned short rh16[16 * 136];  // r*h bf16, same layout

  const int tid  = threadIdx.x;
  const int lane = tid & 63;
  const int w    = tid >> 6;   // 0..7
  const int m16  = lane & 15;  // batch row (N dim)
  const int q    = lane >> 4;

  // Static A-frags: A[m=col][k]; lane m16 = col-in-tile.
  // r-tile: gate cols [16w,+16); u-tile: [128+16w,+16); cand: [16w,+16).
  bf16x8 wr[4], wu[4], wc[4];
  #pragma unroll
  for (int kb = 0; kb < 4; ++kb) {
    bf16x8 fr, fu, fc;
    #pragma unroll
    for (int j = 0; j < 8; ++j) {
      int k = 128 + kb * 32 + q * 8 + j;   // h-part rows
      fr[j] = (short)f2bf(Wg[(size_t)k * 256 + w * 16 + m16]);
      fu[j] = (short)f2bf(Wg[(size_t)k * 256 + 128 + w * 16 + m16]);
      fc[j] = (short)f2bf(Wc[(size_t)k * 128 + w * 16 + m16]);
    }
    wr[kb] = fr; wu[kb] = fu; wc[kb] = fc;
  }

  const int bt = blockIdx.x;          // 0..63
  const int sl = seq_len[bt * 16 + m16];  // per-thread uniform (batch = m16)

  float h0 = 0.f, h1 = 0.f, h2 = 0.f, h3 = 0.f;  // h[m16][16w+q*4+i]

  for (int idx = tid; idx < 16 * 136; idx += 512) h16[idx] = 0;

  const unsigned short* xg = XGC + (size_t)bt * 200 * 6144;
  const int offR = m16 * 384 + w * 16 + q * 4;
  const int offU = offR + 128;
  const int offC = offR + 256;

#define LOADT(t, GA, GU, GC) do { \
    const unsigned short* _b = xg + (size_t)(t) * 6144; \
    GA = *(const u32x2*)(_b + offR); \
    GU = *(const u32x2*)(_b + offU); \
    GC = *(const u32x2*)(_b + offC); } while (0)

  u32x2 gA0, gU0, gC0, gA1, gU1, gC1;
  LOADT(0, gA0, gU0, gC0);
  LOADT(1, gA1, gU1, gC1);
  ldsbar();  // h16 zero-init visible

  const int fragoff = m16 * 136 + q * 8;   // + kb*32 per frag
  const int stoff   = m16 * 136 + w * 16 + q * 4;

#define STEP(T, GA, GU, GC) do { \
    /* ---- P1: gates (B-frags of h: contiguous b128 reads) ---- */ \
    bf16x8 hf0 = __builtin_bit_cast(bf16x8, *(const i32x4*)&h16[fragoff]); \
    bf16x8 hf1 = __builtin_bit_cast(bf16x8, *(const i32x4*)&h16[fragoff + 32]); \
    bf16x8 hf2 = __builtin_bit_cast(bf16x8, *(const i32x4*)&h16[fragoff + 64]); \
    bf16x8 hf3 = __builtin_bit_cast(bf16x8, *(const i32x4*)&h16[fragoff + 96]); \
    f32x4 aR = unpack_bf4(GA), aU = unpack_bf4(GU), aC = unpack_bf4(GC); \
    if ((T) < 198) LOADT((T) + 2, GA, GU, GC); \
    aR = __builtin_amdgcn_mfma_f32_16x16x32_bf16(wr[0], hf0, aR, 0, 0, 0); \
    aU = __builtin_amdgcn_mfma_f32_16x16x32_bf16(wu[0], hf0, aU, 0, 0, 0); \
    aR = __builtin_amdgcn_mfma_f32_16x16x32_bf16(wr[1], hf1, aR, 0, 0, 0); \
    aU = __builtin_amdgcn_mfma_f32_16x16x32_bf16(wu[1], hf1, aU, 0, 0, 0); \
    aR = __builtin_amdgcn_mfma_f32_16x16x32_bf16(wr[2], hf2, aR, 0, 0, 0); \
    aU = __builtin_amdgcn_mfma_f32_16x16x32_bf16(wu[2], hf2, aU, 0, 0, 0); \
    aR = __builtin_amdgcn_mfma_f32_16x16x32_bf16(wr[3], hf3, aR, 0, 0, 0); \
    aU = __builtin_amdgcn_mfma_f32_16x16x32_bf16(wu[3], hf3, aU, 0, 0, 0); \
    float r0 = sigmoid_fast(aR[0]), r1 = sigmoid_fast(aR[1]); \
    float r2 = sigmoid_fast(aR[2]), r3 = sigmoid_fast(aR[3]); \
    float u0 = sigmoid_fast(aU[0]), u1 = sigmoid_fast(aU[1]); \
    float u2 = sigmoid_fast(aU[2]), u3 = sigmoid_fast(aU[3]); \
    /* r*h from registers; one b64 write */ \
    *(u32x2*)&rh16[stoff] = pack_bf4(r0 * h0, r1 * h1, r2 * h2, r3 * h3); \
    ldsbar(); \
    /* ---- P2: candidate + h update ---- */ \
    bf16x8 rf0 = __builtin_bit_cast(bf16x8, *(const i32x4*)&rh16[fragoff]); \
    bf16x8 rf1 = __builtin_bit_cast(bf16x8, *(const i32x4*)&rh16[fragoff + 32]); \
    bf16x8 rf2 = __builtin_bit_cast(bf16x8, *(const i32x4*)&rh16[fragoff + 64]); \
    bf16x8 rf3 = __builtin_bit_cast(bf16x8, *(const i32x4*)&rh16[fragoff + 96]); \
    aC = __builtin_amdgcn_mfma_f32_16x16x32_bf16(wc[0], rf0, aC, 0, 0, 0); \
    aC = __builtin_amdgcn_mfma_f32_16x16x32_bf16(wc[1], rf1, aC, 0, 0, 0); \
    aC = __builtin_amdgcn_mfma_f32_16x16x32_bf16(wc[2], rf2, aC, 0, 0, 0); \
    aC = __builtin_amdgcn_mfma_f32_16x16x32_bf16(wc[3], rf3, aC, 0, 0, 0); \
    float c0 = tanh_fast(aC[0]), c1 = tanh_fast(aC[1]); \
    float c2 = tanh_fast(aC[2]), c3 = tanh_fast(aC[3]); \
    float n0 = u0 * (h0 - c0) + c0, n1 = u1 * (h1 - c1) + c1; \
    float n2 = u2 * (h2 - c2) + c2, n3 = u3 * (h3 - c3) + c3; \
    bool v = (T) < sl; \
    h0 = v ? n0 : h0; h1 = v ? n1 : h1; h2 = v ? n2 : h2; h3 = v ? n3 : h3; \
    f32x4 yv = { v ? n0 : 0.f, v ? n1 : 0.f, v ? n2 : 0.f, v ? n3 : 0.f }; \
    *(f32x4*)(Y + ((size_t)(bt * 16 + m16) * T_SZ + (T)) * 128 + w * 16 + q * 4) = yv; \
    *(u32x2*)&h16[stoff] = pack_bf4(h0, h1, h2, h3); \
    ldsbar(); \
  } while (0)

  for (int t = 0; t < 200; t += 2) {
    STEP(t,     gA0, gU0, gC0);
    STEP(t + 1, gA1, gU1, gC1);
  }
#undef STEP
#undef LOADT
}

extern "C" void kernel_launch(void* const* d_in, const int* in_sizes, int n_in,
                              void* d_out, int out_size, void* d_ws, size_t ws_size,
                              hipStream_t stream) {
  const float* X   = (const float*)d_in[0];
  const int*   seq = (const int*)  d_in[1];
  const float* Wg  = (const float*)d_in[2];
  const float* bg  = (const float*)d_in[3];
  const float* Wc  = (const float*)d_in[4];
  const float* bc  = (const float*)d_in[5];
  float* Y = (float*)d_out;
  unsigned short* XGC = (unsigned short*)d_ws;  // 64*200*16*384 bf16 = 157 MB

  hipLaunchKernelGGL(xproj_kernel, dim3(1600), dim3(256), 0, stream, X, Wg, bg, Wc, bc, XGC);
  hipLaunchKernelGGL(gru_kernel,   dim3(64),   dim3(512), 0, stream, XGC, seq, Wg, Wc, Y);
}